// Round 1
// baseline (1124.833 us; speedup 1.0000x reference)
//
#include <hip/hip_runtime.h>

typedef __attribute__((ext_vector_type(8))) short short8;
typedef __attribute__((ext_vector_type(4))) float floatx4;
typedef __attribute__((ext_vector_type(4))) unsigned uintx4;

#define NSTEPS 5
#define DD 512
#define ANN 256
#define NNODE 2048
#define NEDGE 8                 // 2*E
#define NCOLS (NNODE * NEDGE)   // 16384
#define MAXE 96                 // nnz per (node,edge-type): mean 30.7, sd 5.5
#define KP (NEDGE * DD)         // 4096

// Fragment-ordered (FO) layout for [M][K] bf16:
// addr(row,k) = ((row>>4)*(K>>3) + (k>>3))*128 + ((row&15)<<3) + (k&7)
// One slot = 16 rows x 32 k = 1KB, lane l's 16B at slot_base + l*16.

typedef __attribute__((address_space(3))) unsigned lds_u32;
typedef const __attribute__((address_space(1))) unsigned g_u32;
__device__ __forceinline__ void gload16(const short* g, short* l) {
    __builtin_amdgcn_global_load_lds((g_u32*)g, (lds_u32*)l, 16, 0, 0);
}

__device__ inline float bf2f(unsigned short s) {
    unsigned u = ((unsigned)s) << 16;
    float f; __builtin_memcpy(&f, &u, 4);
    return f;
}
__device__ inline unsigned short f2bf(float f) {   // round-to-nearest-even
    unsigned u; __builtin_memcpy(&u, &f, 4);
    u += 0x7fffu + ((u >> 16) & 1u);
    return (unsigned short)(u >> 16);
}
__device__ inline void split2(float x, unsigned short& hi, unsigned short& lo) {
    hi = f2bf(x);
    lo = f2bf(x - bf2f(hi));
}
// split-write one element into FO hi/lo planes (K=512)
__device__ inline void fo_write(short* __restrict__ Fhi, short* __restrict__ Flo,
                                int row, int col, float v) {
    unsigned short hs, ls;
    split2(v, hs, ls);
    size_t a = ((size_t)(row >> 4) * 64 + (col >> 3)) * 128 + ((row & 15) << 3) + (col & 7);
    Fhi[a] = (short)hs;
    Flo[a] = (short)ls;
}
// split-write a pair of adjacent cols (c even) as one u32 per plane
__device__ inline void fo_write2(short* __restrict__ Fhi, short* __restrict__ Flo,
                                 int row, int c, float v0, float v1) {
    unsigned short h0, l0, h1, l1;
    split2(v0, h0, l0);
    split2(v1, h1, l1);
    size_t a = ((size_t)(row >> 4) * 64 + (c >> 3)) * 128 + ((row & 15) << 3) + (c & 7);
    *(unsigned*)(Fhi + a) = (unsigned)h0 | ((unsigned)h1 << 16);
    *(unsigned*)(Flo + a) = (unsigned)l0 | ((unsigned)l1 << 16);
}

// h = [ann | 0] fp32 (+1 zero row at index NNODE for gather padding);
// HB (FO, K=512) = split(h); cnt2 = 0; idx pre-filled with zero-row index.
__global__ __launch_bounds__(256) void k_init(const float* __restrict__ ann,
                                              float* __restrict__ h,
                                              short* __restrict__ HBhi,
                                              short* __restrict__ HBlo,
                                              int* __restrict__ cnt2,
                                              unsigned short* __restrict__ idx) {
    int n = blockIdx.x, t = threadIdx.x;
    int c = 2 * t;
    float v0 = 0.f, v1 = 0.f;
    if (c < ANN) {
        v0 = ann[(size_t)n * ANN + c];
        v1 = ann[(size_t)n * ANN + c + 1];
    }
    h[(size_t)n * DD + c]     = v0;
    h[(size_t)n * DD + c + 1] = v1;
    fo_write2(HBhi, HBlo, n, c, v0, v1);
    if (t < NEDGE) cnt2[n * NEDGE + t] = 0;
    // pre-fill this node's index lists with the zero-row index (2048):
    // k_build overwrites the first cnt entries, the rest act as padding.
    unsigned* ip = (unsigned*)(idx + (size_t)n * NEDGE * MAXE);
    for (int j = t; j < NEDGE * MAXE / 2; j += 256)
        ip[j] = 2048u | (2048u << 16);
    if (n == 0) {   // zero row for padded gather loads
        h[(size_t)NNODE * DD + c]     = 0.f;
        h[(size_t)NNODE * DD + c + 1] = 0.f;
    }
}

// fp32 0/1 adjacency -> per-(row, edge-type) source-node index lists
__global__ __launch_bounds__(256) void k_build(const float* __restrict__ adj,
                                               int* __restrict__ cnt2,
                                               unsigned short* __restrict__ idx) {
    int n = blockIdx.x;
    const float* row = adj + (size_t)n * NCOLS;
    for (int j8 = threadIdx.x; j8 < NCOLS / 8; j8 += 256) {
        floatx4 a = *(const floatx4*)(row + j8 * 8);
        floatx4 b = *(const floatx4*)(row + j8 * 8 + 4);
        unsigned nz = 0;
        #pragma unroll
        for (int i = 0; i < 4; i++) {
            if (a[i] != 0.f) nz |= 1u << i;
            if (b[i] != 0.f) nz |= 1u << (4 + i);
        }
        while (nz) {
            int i = __builtin_ctz(nz);
            nz &= nz - 1;
            int j = j8 * 8 + i;
            int e = j >> 11;
            int m = j & (NNODE - 1);
            int p = atomicAdd(&cnt2[n * NEDGE + e], 1);
            if (p < MAXE) idx[((size_t)n * NEDGE + e) * MAXE + p] = (unsigned short)m;
        }
    }
}

// Transpose+split weights into FO (hi & lo), contiguous-K source [K][512]
__global__ __launch_bounds__(256) void k_transP(const float* __restrict__ W,
                                                short* __restrict__ Fhi,
                                                short* __restrict__ Flo, int K) {
    __shared__ float st[32][33];
    int tx = threadIdx.x & 31, ty = threadIdx.x >> 5;
    int k0 = blockIdx.x * 32, n0 = blockIdx.y * 32;
    #pragma unroll
    for (int i = 0; i < 4; i++)
        st[ty + i * 8][tx] = W[(size_t)(k0 + ty + i * 8) * DD + n0 + tx];
    __syncthreads();
    #pragma unroll
    for (int i = 0; i < 4; i++) {
        int n = n0 + ty + i * 8, k = k0 + tx;
        float v = st[tx][ty + i * 8];
        unsigned short hs, ls;
        split2(v, hs, ls);
        size_t a = ((size_t)(n >> 4) * (K >> 3) + (k >> 3)) * 128 + ((n & 15) << 3) + (k & 7);
        Fhi[a] = (short)hs;
        Flo[a] = (short)ls;
    }
}

// Same, 4-quadrant source (k-half x n-half), K=1024
__global__ __launch_bounds__(256) void k_transG(const float* __restrict__ s00,
                                                const float* __restrict__ s10,
                                                const float* __restrict__ s01,
                                                const float* __restrict__ s11,
                                                short* __restrict__ Fhi,
                                                short* __restrict__ Flo) {
    __shared__ float st[32][33];
    const int K = 2 * DD;
    int tx = threadIdx.x & 31, ty = threadIdx.x >> 5;
    int k0 = blockIdx.x * 32, n0 = blockIdx.y * 32;
    const float* sk0 = (n0 < DD) ? s00 : s01;
    const float* sk1 = (n0 < DD) ? s10 : s11;
    #pragma unroll
    for (int i = 0; i < 4; i++) {
        int k = k0 + ty + i * 8;
        const float* s = (k < DD) ? sk0 : sk1;
        st[ty + i * 8][tx] = s[(size_t)(k & (DD - 1)) * DD + ((n0 + tx) & (DD - 1))];
    }
    __syncthreads();
    #pragma unroll
    for (int i = 0; i < 4; i++) {
        int n = n0 + ty + i * 8, k = k0 + tx;
        float v = st[tx][ty + i * 8];
        unsigned short hs, ls;
        split2(v, hs, ls);
        size_t a = ((size_t)(n >> 4) * (K >> 3) + (k >> 3)) * 128 + ((n & 15) << 3) + (k & 7);
        Fhi[a] = (short)hs;
        Flo[a] = (short)ls;
    }
}

// All-edge gather, latency-optimized:
// grid 4096 = 8 XCD-bands x 256 (node,half) pairs. Each block: one node, 4 edges.
// 256 threads = 128 column-threads x 2 edge-groups; each thread 2 edges serially.
// Index lists padded (by k_init pre-fill) to multiples of 8 with zero-row index
// 2048 -> branch-free batch-8 rounds (8 loads in flight, dual accumulators),
// no serial tail chains. XCD-banded node mapping so the 4 nodes sharing each
// 64B FO line are written from the same XCD (kills partial-line write amp).
__global__ __launch_bounds__(256) void k_gather_all(const float* __restrict__ h,
                                                    const int* __restrict__ cnt2,
                                                    const unsigned short* __restrict__ idx,
                                                    short* __restrict__ Gbhi,
                                                    short* __restrict__ Gblo) {
    __shared__ unsigned short sidx[4 * MAXE];
    __shared__ int scnt[4];
    const int b = blockIdx.x;
    const int x = b & 7;               // XCD (round-robin dispatch assumed)
    const int u = b >> 3;              // 0..511
    const int n = x * 256 + (u >> 1);  // nodes banded per XCD
    const int half = u & 1;            // edge half: edges half*4 .. half*4+3
    const int t = threadIdx.x;
    const int th = t & 127;            // cols 4*th .. 4*th+3
    const int eg = t >> 7;             // edge pair within half

    if (t < 4) scnt[t] = cnt2[n * NEDGE + half * 4 + t];
    {
        const unsigned* src = (const unsigned*)(idx + ((size_t)n * NEDGE + half * 4) * MAXE);
        if (t < 4 * MAXE / 2) ((unsigned*)sidx)[t] = src[t];
    }
    __syncthreads();

    const float* hp = h + 4 * th;
    size_t wbase = ((size_t)(n >> 4) * 512) * 128 + ((n & 15) << 3) + ((th & 1) << 2);

    #pragma unroll 1
    for (int ee = 0; ee < 2; ee++) {
        const int el = eg * 2 + ee;        // local edge 0..3
        const int ge = half * 4 + el;      // global edge 0..7
        int m = scnt[el];
        m = m > MAXE ? MAXE : m;
        m = (m + 7) & ~7;                  // padded entries point at zero row
        const unsigned short* row = &sidx[el * MAXE];
        floatx4 a0 = (floatx4){0.f, 0.f, 0.f, 0.f};
        floatx4 a1 = (floatx4){0.f, 0.f, 0.f, 0.f};
        for (int i = 0; i < m; i += 8) {
            uintx4 w = *(const uintx4*)(row + i);   // 8 indices, one LDS b128
            floatx4 v0 = *(const floatx4*)(hp + (size_t)(w[0] & 0xffffu) * DD);
            floatx4 v1 = *(const floatx4*)(hp + (size_t)(w[0] >> 16) * DD);
            floatx4 v2 = *(const floatx4*)(hp + (size_t)(w[1] & 0xffffu) * DD);
            floatx4 v3 = *(const floatx4*)(hp + (size_t)(w[1] >> 16) * DD);
            floatx4 v4 = *(const floatx4*)(hp + (size_t)(w[2] & 0xffffu) * DD);
            floatx4 v5 = *(const floatx4*)(hp + (size_t)(w[2] >> 16) * DD);
            floatx4 v6 = *(const floatx4*)(hp + (size_t)(w[3] & 0xffffu) * DD);
            floatx4 v7 = *(const floatx4*)(hp + (size_t)(w[3] >> 16) * DD);
            a0 += v0; a1 += v1; a0 += v2; a1 += v3;
            a0 += v4; a1 += v5; a0 += v6; a1 += v7;
        }
        floatx4 a = a0 + a1;

        unsigned short hs[4], ls[4];
        #pragma unroll
        for (int j = 0; j < 4; j++) split2(a[j], hs[j], ls[j]);
        unsigned long long hpk = (unsigned long long)hs[0] | ((unsigned long long)hs[1] << 16)
                               | ((unsigned long long)hs[2] << 32) | ((unsigned long long)hs[3] << 48);
        unsigned long long lpk = (unsigned long long)ls[0] | ((unsigned long long)ls[1] << 16)
                               | ((unsigned long long)ls[2] << 32) | ((unsigned long long)ls[3] << 48);
        size_t addr = wbase + (size_t)(ge * 64 + (th >> 1)) * 128;
        __builtin_nontemporal_store(hpk, (unsigned long long*)(Gbhi + addr));
        __builtin_nontemporal_store(lpk, (unsigned long long*)(Gblo + addr));
    }
}

// Split-bf16 MFMA GEMM on FO operands (m97 structure: single 24 KB LDS buffer,
// global_load_lds(16B) staging, 2 barriers/iter). Block 64(M)x32(N), 4 waves
// (2m x 2n), wave 32x16. C = (Ahi+Alo)@(Bhi+Blo)^T (3 products), fp32 acc.
// 1D grids of 1024 blocks (4/CU):
// MODE 0 (prop): K split 2 (kh): block K=2048 of Gbig@WpT; P[kh][o] = acc.
// MODE 1 (zr):   K=1024 (A seg: Ga|HB), N=1024. col<512: zbuf=sigmoid(v+b0);
//                else RH = split(sigmoid(v+b1)*h).
// MODE 2 (fin):  seg split (kh): kh=0: Ga@Wh (K=512), kh=1: RH@Uh; P[kh][o]=acc.
template<int MODE>
__global__ __launch_bounds__(256, 4) void k_gemm8(
    const short* __restrict__ A0hi, const short* __restrict__ A0lo,
    const short* __restrict__ A1hi, const short* __restrict__ A1lo,
    const short* __restrict__ Bhi,  const short* __restrict__ Blo,
    const float* __restrict__ bias0, const float* __restrict__ bias1,
    float* __restrict__ zbuf,
    float* __restrict__ h,
    short* __restrict__ Ohi, short* __restrict__ Olo,
    float* __restrict__ P0, float* __restrict__ P1) {

    __shared__ short S[24][512];   // 24 slots x 1KB = 24 KB (single buffer)

    const int tid = threadIdx.x;
    const int lane = tid & 63;
    const int wave = tid >> 6;
    const int wm = wave >> 1;          // m-half (32 rows)
    const int wn = wave & 1;           // n-tile (16 cols)
    const int quad = lane >> 4;
    const int l16 = lane & 15;

    // 1D grid decode (XCD-banded: dispatch round-robin pbid%8 assumed)
    const int pbid = blockIdx.x;
    const int x = pbid & 7;
    const int j = pbid >> 3;           // 0..127
    const int mband = x * 4 + (j & 3); // 0..31
    int kh, bx;
    if (MODE == 1) { kh = 0; bx = j >> 2; }            // bx 0..31
    else           { kh = (j >> 2) & 1; bx = j >> 3; } // bx 0..15
    const int blockM = mband * 64;
    const int blockN = bx * 32;
    const int mt0 = blockM >> 4, nt0 = blockN >> 4;
    const int KCB = (MODE == 0) ? 512 : 128;           // B row stride (kchunks)
    const int bko = (MODE == 0) ? kh * 256 : (MODE == 2 ? kh * 64 : 0);
    const int Kloc = (MODE == 0) ? 2048 : (MODE == 1 ? 1024 : 512);

    const short* Ahi_s = (MODE == 2 && kh) ? A1hi : A0hi;
    const short* Alo_s = (MODE == 2 && kh) ? A1lo : A0lo;

    floatx4 acc[2];
    acc[0] = (floatx4){0.f, 0.f, 0.f, 0.f};
    acc[1] = (floatx4){0.f, 0.f, 0.f, 0.f};

    // slots: 0..7 A-hi (mt=u>>1, ks=u&1); 8..15 A-lo; 16..23 B (pl=u>>2, ks=(u>>1)&1, nt=u&1)
    auto gaddr = [&](int k0, int s) -> const short* {
        if (s < 16) {
            int pl = s >> 3, u = s & 7;
            int mt = u >> 1, ks = u & 1;
            const short* base;
            int kc, stride;
            if (MODE == 0) {
                base = pl ? A0lo : A0hi;
                kc = kh * 256 + (k0 >> 3) + ks * 4;
                stride = 512;
            } else if (MODE == 1) {
                int seg = k0 >> 9;
                base = seg ? (pl ? A1lo : A1hi) : (pl ? A0lo : A0hi);
                kc = ((k0 & 511) >> 3) + ks * 4;
                stride = 64;
            } else {
                base = pl ? Alo_s : Ahi_s;
                kc = (k0 >> 3) + ks * 4;
                stride = 64;
            }
            return base + ((size_t)(mt0 + mt) * stride + kc) * 128;
        } else {
            int u = s - 16, pl = u >> 2, ks = (u >> 1) & 1, nt = u & 1;
            const short* base = pl ? Blo : Bhi;
            return base + ((size_t)(nt0 + nt) * KCB + bko + (k0 >> 3) + ks * 4) * 128;
        }
    };

    for (int k0 = 0; k0 < Kloc; k0 += 64) {
        // stage: each wave DMAs 6 slots (wave-uniform LDS base + lane*16)
        #pragma unroll
        for (int jj = 0; jj < 6; jj++) {
            int s = jj * 4 + wave;
            gload16(gaddr(k0, s) + lane * 8, &S[s][lane * 8]);
        }
        __syncthreads();   // drains DMA (vmcnt) + ensures all waves staged

        #pragma unroll
        for (int ks = 0; ks < 2; ks++) {
            short8 ah[2], al[2], bh, bl;
            #pragma unroll
            for (int mi = 0; mi < 2; mi++) {
                ah[mi] = *(const short8*)&S[(wm * 2 + mi) * 2 + ks][lane * 8];
                al[mi] = *(const short8*)&S[8 + (wm * 2 + mi) * 2 + ks][lane * 8];
            }
            bh = *(const short8*)&S[16 + ks * 2 + wn][lane * 8];
            bl = *(const short8*)&S[20 + ks * 2 + wn][lane * 8];
            #pragma unroll
            for (int mi = 0; mi < 2; mi++) {
                acc[mi] = __builtin_amdgcn_mfma_f32_16x16x32_bf16(ah[mi], bh, acc[mi], 0, 0, 0);
                acc[mi] = __builtin_amdgcn_mfma_f32_16x16x32_bf16(ah[mi], bl, acc[mi], 0, 0, 0);
                acc[mi] = __builtin_amdgcn_mfma_f32_16x16x32_bf16(al[mi], bh, acc[mi], 0, 0, 0);
            }
        }
        __syncthreads();   // all reads done before next stage overwrites
    }

    // C/D layout (m89-verified): elem r -> row = quad*4+r, col = l16
    float* P = kh ? P1 : P0;
    #pragma unroll
    for (int mi = 0; mi < 2; mi++) {
        int gcol = blockN + wn * 16 + l16;
        #pragma unroll
        for (int r = 0; r < 4; r++) {
            int grow = blockM + wm * 32 + mi * 16 + quad * 4 + r;
            float v = acc[mi][r];
            if (MODE == 0 || MODE == 2) {
                P[(size_t)grow * DD + gcol] = v;
            } else {
                if (gcol < DD) {
                    size_t o = (size_t)grow * DD + gcol;
                    zbuf[o] = 1.f / (1.f + __expf(-(v + bias0[gcol])));
                } else {
                    int c = gcol - DD;
                    size_t o = (size_t)grow * DD + c;
                    float rr = 1.f / (1.f + __expf(-(v + bias1[c])));
                    fo_write(Ohi, Olo, grow, c, rr * h[o]);
                }
            }
        }
    }
}

// Ga = split(P0 + P1 + deg-bias), deg-bias = sum_e cnt[n,e]*b_prop[e] computed inline
__global__ __launch_bounds__(256) void k_combP(const float* __restrict__ P0,
                                               const float* __restrict__ P1,
                                               const int* __restrict__ cnt2,
                                               const float* __restrict__ bp,
                                               short* __restrict__ Gahi,
                                               short* __restrict__ Galo) {
    int n = blockIdx.x, t = threadIdx.x;
    int c = 2 * t;
    float s0 = 0.f, s1 = 0.f;
    #pragma unroll
    for (int e = 0; e < NEDGE; e++) {
        float ce = (float)cnt2[n * NEDGE + e];
        s0 += ce * bp[e * DD + c];
        s1 += ce * bp[e * DD + c + 1];
    }
    size_t o = (size_t)n * DD + c;
    float v0 = P0[o] + P1[o] + s0;
    float v1 = P0[o + 1] + P1[o + 1] + s1;
    fo_write2(Gahi, Galo, n, c, v0, v1);
}

// GRU combine: hn = (1-z)h + z*tanh(P0+P1+bh) -> h, HB (FO), outF
__global__ __launch_bounds__(256) void k_combF(const float* __restrict__ P0,
                                               const float* __restrict__ P1,
                                               const float* __restrict__ bh,
                                               const float* __restrict__ zbuf,
                                               float* __restrict__ h,
                                               short* __restrict__ HBhi,
                                               short* __restrict__ HBlo,
                                               float* __restrict__ outF) {
    int n = blockIdx.x, t = threadIdx.x;
    int c = 2 * t;
    size_t o = (size_t)n * DD + c;
    float hn0, hn1;
    {
        float v = P0[o] + P1[o] + bh[c];
        hn0 = (1.f - zbuf[o]) * h[o] + zbuf[o] * tanhf(v);
    }
    {
        float v = P0[o + 1] + P1[o + 1] + bh[c + 1];
        hn1 = (1.f - zbuf[o + 1]) * h[o + 1] + zbuf[o + 1] * tanhf(v);
    }
    h[o] = hn0;
    h[o + 1] = hn1;
    fo_write2(HBhi, HBlo, n, c, hn0, hn1);
    outF[o] = hn0;
    outF[o + 1] = hn1;
}

extern "C" void kernel_launch(void* const* d_in, const int* in_sizes, int n_in,
                              void* d_out, int out_size, void* d_ws, size_t ws_size,
                              hipStream_t stream) {
    const float* adj = (const float*)d_in[0];
    const float* ann = (const float*)d_in[1];
    const float* Wp  = (const float*)d_in[2];
    const float* bp  = (const float*)d_in[3];
    const float* Wz  = (const float*)d_in[4];
    const float* Uz  = (const float*)d_in[5];
    const float* bz  = (const float*)d_in[6];
    const float* Wr  = (const float*)d_in[7];
    const float* Ur  = (const float*)d_in[8];
    const float* br  = (const float*)d_in[9];
    const float* Wh  = (const float*)d_in[10];
    const float* Uh  = (const float*)d_in[11];
    const float* bh  = (const float*)d_in[12];

    // workspace carve (~77 MB; ws ~512 MB per round-4 fill counters)
    char* p = (char*)d_ws;
    float* h     = (float*)p; p += (size_t)(NNODE + 1) * DD * 4;    // 4 MB (+zero row)
    float* abuf  = (float*)p; p += (size_t)NNODE * DD * 4;          // 4 MB z-buffer
    float* P0    = (float*)p; p += (size_t)NNODE * DD * 4;          // 4 MB split-K partial
    float* P1    = (float*)p; p += (size_t)NNODE * DD * 4;          // 4 MB
    short* Gbhi  = (short*)p; p += (size_t)NNODE * KP * 2;          // 16 MB (FO K=4096)
    short* Gblo  = (short*)p; p += (size_t)NNODE * KP * 2;          // 16 MB
    short* Gahi  = (short*)p; p += (size_t)NNODE * DD * 2;          // 2 MB (FO K=512)
    short* Galo  = (short*)p; p += (size_t)NNODE * DD * 2;
    short* HBhi  = (short*)p; p += (size_t)NNODE * DD * 2;
    short* HBlo  = (short*)p; p += (size_t)NNODE * DD * 2;
    short* RHhi  = (short*)p; p += (size_t)NNODE * DD * 2;
    short* RHlo  = (short*)p; p += (size_t)NNODE * DD * 2;
    short* WpThi = (short*)p; p += (size_t)DD * KP * 2;             // 4 MB (FO N=512,K=4096)
    short* WpTlo = (short*)p; p += (size_t)DD * KP * 2;
    short* ZRhi  = (short*)p; p += (size_t)(2 * DD) * (2 * DD) * 2; // 2 MB (FO N=1024,K=1024)
    short* ZRlo  = (short*)p; p += (size_t)(2 * DD) * (2 * DD) * 2;
    short* HThi  = (short*)p; p += (size_t)DD * (2 * DD) * 2;       // 1 MB (FO N=512,K=1024)
    short* HTlo  = (short*)p; p += (size_t)DD * (2 * DD) * 2;
    unsigned short* idx = (unsigned short*)p;
    p += (size_t)NNODE * NEDGE * MAXE * 2;                          // 3 MB
    int* cnt2 = (int*)p; p += (size_t)NNODE * NEDGE * 4;

    float* outF = (float*)d_out;

    k_init<<<NNODE, 256, 0, stream>>>(ann, h, HBhi, HBlo, cnt2, idx);
    k_build<<<NNODE, 256, 0, stream>>>(adj, cnt2, idx);
    k_transP<<<dim3(KP / 32, DD / 32), 256, 0, stream>>>(Wp, WpThi, WpTlo, KP);
    k_transG<<<dim3(32, 32), 256, 0, stream>>>(Wz, Uz, Wr, Ur, ZRhi, ZRlo);
    k_transG<<<dim3(32, 16), 256, 0, stream>>>(Wh, Uh, Wh, Uh, HThi, HTlo);

    for (int s = 0; s < NSTEPS; s++) {
        k_gather_all<<<2 * NNODE, 256, 0, stream>>>(h, cnt2, idx, Gbhi, Gblo);
        // prop split-K: P0/P1 = Gbig @ WpT halves
        k_gemm8<0><<<1024, 256, 0, stream>>>(Gbhi, Gblo, nullptr, nullptr,
                                             WpThi, WpTlo, nullptr, nullptr,
                                             nullptr, nullptr, nullptr, nullptr, P0, P1);
        // Ga = split(P0 + P1 + deg-bias)
        k_combP<<<NNODE, 256, 0, stream>>>(P0, P1, cnt2, bp, Gahi, Galo);
        // [z|r]: z -> abuf (fp32), RH = split(sigmoid(.)*h)
        k_gemm8<1><<<1024, 256, 0, stream>>>(Gahi, Galo, HBhi, HBlo,
                                             ZRhi, ZRlo, bz, br,
                                             abuf, h, RHhi, RHlo, nullptr, nullptr);
        // fin split: P0 = Ga@Wh, P1 = RH@Uh
        k_gemm8<2><<<1024, 256, 0, stream>>>(Gahi, Galo, RHhi, RHlo,
                                             HThi, HTlo, nullptr, nullptr,
                                             nullptr, nullptr, nullptr, nullptr, P0, P1);
        // h' = (1-z)h + z*tanh(P0+P1+bh) -> h, HB, d_out
        k_combF<<<NNODE, 256, 0, stream>>>(P0, P1, bh, abuf, h, HBhi, HBlo, outF);
    }
}

// Round 2
// 906.813 us; speedup vs baseline: 1.2404x; 1.2404x over previous
//
#include <hip/hip_runtime.h>

typedef __attribute__((ext_vector_type(8))) short short8;
typedef __attribute__((ext_vector_type(4))) float floatx4;
typedef __attribute__((ext_vector_type(2))) unsigned uintx2;

#define NSTEPS 5
#define DD 512
#define ANN 256
#define NNODE 2048
#define NEDGE 8                 // 2*E
#define NCOLS (NNODE * NEDGE)   // 16384
#define MAXE 96                 // nnz per (node,edge-type): mean 30.7, sd 5.5
#define KP (NEDGE * DD)         // 4096

// Fragment-ordered (FO) layout for [M][K] bf16:
// addr(row,k) = ((row>>4)*(K>>3) + (k>>3))*128 + ((row&15)<<3) + (k&7)
// One slot = 16 rows x 32 k = 1KB, lane l's 16B at slot_base + l*16.

typedef __attribute__((address_space(3))) unsigned lds_u32;
typedef const __attribute__((address_space(1))) unsigned g_u32;
__device__ __forceinline__ void gload16(const short* g, short* l) {
    __builtin_amdgcn_global_load_lds((g_u32*)g, (lds_u32*)l, 16, 0, 0);
}

__device__ inline float bf2f(unsigned short s) {
    unsigned u = ((unsigned)s) << 16;
    float f; __builtin_memcpy(&f, &u, 4);
    return f;
}
__device__ inline unsigned short f2bf(float f) {   // round-to-nearest-even
    unsigned u; __builtin_memcpy(&u, &f, 4);
    u += 0x7fffu + ((u >> 16) & 1u);
    return (unsigned short)(u >> 16);
}
__device__ inline void split2(float x, unsigned short& hi, unsigned short& lo) {
    hi = f2bf(x);
    lo = f2bf(x - bf2f(hi));
}
// split-write one element into FO hi/lo planes (K=512)
__device__ inline void fo_write(short* __restrict__ Fhi, short* __restrict__ Flo,
                                int row, int col, float v) {
    unsigned short hs, ls;
    split2(v, hs, ls);
    size_t a = ((size_t)(row >> 4) * 64 + (col >> 3)) * 128 + ((row & 15) << 3) + (col & 7);
    Fhi[a] = (short)hs;
    Flo[a] = (short)ls;
}
// split-write a pair of adjacent cols (c even) as one u32 per plane
__device__ inline void fo_write2(short* __restrict__ Fhi, short* __restrict__ Flo,
                                 int row, int c, float v0, float v1) {
    unsigned short h0, l0, h1, l1;
    split2(v0, h0, l0);
    split2(v1, h1, l1);
    size_t a = ((size_t)(row >> 4) * 64 + (c >> 3)) * 128 + ((row & 15) << 3) + (c & 7);
    *(unsigned*)(Fhi + a) = (unsigned)h0 | ((unsigned)h1 << 16);
    *(unsigned*)(Flo + a) = (unsigned)l0 | ((unsigned)l1 << 16);
}

// h = [ann | 0] fp32 (+1 zero row at index NNODE for gather padding);
// HB (FO, K=512) = split(h); cnt2 = 0; idx pre-filled with zero-row index.
__global__ __launch_bounds__(256) void k_init(const float* __restrict__ ann,
                                              float* __restrict__ h,
                                              short* __restrict__ HBhi,
                                              short* __restrict__ HBlo,
                                              int* __restrict__ cnt2,
                                              unsigned short* __restrict__ idx) {
    int n = blockIdx.x, t = threadIdx.x;
    int c = 2 * t;
    float v0 = 0.f, v1 = 0.f;
    if (c < ANN) {
        v0 = ann[(size_t)n * ANN + c];
        v1 = ann[(size_t)n * ANN + c + 1];
    }
    h[(size_t)n * DD + c]     = v0;
    h[(size_t)n * DD + c + 1] = v1;
    fo_write2(HBhi, HBlo, n, c, v0, v1);
    if (t < NEDGE) cnt2[n * NEDGE + t] = 0;
    // pre-fill this node's index lists with the zero-row index (2048):
    // k_build overwrites the first cnt entries, the rest act as padding.
    unsigned* ip = (unsigned*)(idx + (size_t)n * NEDGE * MAXE);
    for (int j = t; j < NEDGE * MAXE / 2; j += 256)
        ip[j] = 2048u | (2048u << 16);
    if (n == 0) {   // zero row for padded gather loads
        h[(size_t)NNODE * DD + c]     = 0.f;
        h[(size_t)NNODE * DD + c + 1] = 0.f;
    }
}

// fp32 0/1 adjacency -> per-(row, edge-type) source-node index lists
__global__ __launch_bounds__(256) void k_build(const float* __restrict__ adj,
                                               int* __restrict__ cnt2,
                                               unsigned short* __restrict__ idx) {
    int n = blockIdx.x;
    const float* row = adj + (size_t)n * NCOLS;
    for (int j8 = threadIdx.x; j8 < NCOLS / 8; j8 += 256) {
        floatx4 a = *(const floatx4*)(row + j8 * 8);
        floatx4 b = *(const floatx4*)(row + j8 * 8 + 4);
        unsigned nz = 0;
        #pragma unroll
        for (int i = 0; i < 4; i++) {
            if (a[i] != 0.f) nz |= 1u << i;
            if (b[i] != 0.f) nz |= 1u << (4 + i);
        }
        while (nz) {
            int i = __builtin_ctz(nz);
            nz &= nz - 1;
            int j = j8 * 8 + i;
            int e = j >> 11;
            int m = j & (NNODE - 1);
            int p = atomicAdd(&cnt2[n * NEDGE + e], 1);
            if (p < MAXE) idx[((size_t)n * NEDGE + e) * MAXE + p] = (unsigned short)m;
        }
    }
}

// Transpose+split weights into FO (hi & lo), contiguous-K source [K][512]
__global__ __launch_bounds__(256) void k_transP(const float* __restrict__ W,
                                                short* __restrict__ Fhi,
                                                short* __restrict__ Flo, int K) {
    __shared__ float st[32][33];
    int tx = threadIdx.x & 31, ty = threadIdx.x >> 5;
    int k0 = blockIdx.x * 32, n0 = blockIdx.y * 32;
    #pragma unroll
    for (int i = 0; i < 4; i++)
        st[ty + i * 8][tx] = W[(size_t)(k0 + ty + i * 8) * DD + n0 + tx];
    __syncthreads();
    #pragma unroll
    for (int i = 0; i < 4; i++) {
        int n = n0 + ty + i * 8, k = k0 + tx;
        float v = st[tx][ty + i * 8];
        unsigned short hs, ls;
        split2(v, hs, ls);
        size_t a = ((size_t)(n >> 4) * (K >> 3) + (k >> 3)) * 128 + ((n & 15) << 3) + (k & 7);
        Fhi[a] = (short)hs;
        Flo[a] = (short)ls;
    }
}

// Same, 4-quadrant source (k-half x n-half), K=1024
__global__ __launch_bounds__(256) void k_transG(const float* __restrict__ s00,
                                                const float* __restrict__ s10,
                                                const float* __restrict__ s01,
                                                const float* __restrict__ s11,
                                                short* __restrict__ Fhi,
                                                short* __restrict__ Flo) {
    __shared__ float st[32][33];
    const int K = 2 * DD;
    int tx = threadIdx.x & 31, ty = threadIdx.x >> 5;
    int k0 = blockIdx.x * 32, n0 = blockIdx.y * 32;
    const float* sk0 = (n0 < DD) ? s00 : s01;
    const float* sk1 = (n0 < DD) ? s10 : s11;
    #pragma unroll
    for (int i = 0; i < 4; i++) {
        int k = k0 + ty + i * 8;
        const float* s = (k < DD) ? sk0 : sk1;
        st[ty + i * 8][tx] = s[(size_t)(k & (DD - 1)) * DD + ((n0 + tx) & (DD - 1))];
    }
    __syncthreads();
    #pragma unroll
    for (int i = 0; i < 4; i++) {
        int n = n0 + ty + i * 8, k = k0 + tx;
        float v = st[tx][ty + i * 8];
        unsigned short hs, ls;
        split2(v, hs, ls);
        size_t a = ((size_t)(n >> 4) * (K >> 3) + (k >> 3)) * 128 + ((n & 15) << 3) + (k & 7);
        Fhi[a] = (short)hs;
        Flo[a] = (short)ls;
    }
}

// All-edge gather, full-line-write version.
// Finding (R0/R1 counters): gather dur is proportional to HBM bytes at
// ~1.6 MB/us; partial-line (16B-per-block) FO writes caused 2-3.3x write amp.
// Fix: block = 4 consecutive nodes x 2 edge types (grid 2048). Wave dn owns
// node n0+dn; lane th2 owns cols 8*th2..8*th2+7. A 64B FO line = exactly the
// 4 nodes of this block -> after a barrier, the 4 waves' 16B chunks land
// back-to-back and merge to full dirty lines in L2 (no RFO, no nt hint;
// Gb stays cache-resident for k_gemm8<0> which reads it next).
__global__ __launch_bounds__(256) void k_gather_all(const float* __restrict__ h,
                                                    const int* __restrict__ cnt2,
                                                    const unsigned short* __restrict__ idx,
                                                    short* __restrict__ Gbhi,
                                                    short* __restrict__ Gblo) {
    __shared__ unsigned short sidx[8 * MAXE];   // [dn][le][96]
    __shared__ int scnt[8];
    const int bid = blockIdx.x;
    const int ep = bid & 3;            // edge pair: edges 2ep, 2ep+1
    const int g  = bid >> 2;           // node group 0..511
    const int n0 = g * 4;
    const int t  = threadIdx.x;
    const int dn = t >> 6;             // wave = node offset 0..3
    const int th2 = t & 63;            // cols 8*th2 .. 8*th2+7

    if (t < 8) scnt[t] = cnt2[(n0 + (t >> 1)) * NEDGE + 2 * ep + (t & 1)];
    {
        // 8 lists x 96 u16 = 384 u32; node d's two lists are contiguous (96 u32)
        const unsigned* src0 = (const unsigned*)(idx + ((size_t)n0 * NEDGE + 2 * ep) * MAXE);
        for (int j = t; j < 384; j += 256) {
            int d = j / 96;
            int w = j - d * 96;
            ((unsigned*)sidx)[d * 96 + w] = src0[(size_t)d * (NEDGE * MAXE / 2) + w];
        }
    }
    __syncthreads();

    const float* hp = h + 8 * th2;

    floatx4 e0c0, e0c1, e1c0, e1c1;
    auto gather_edge = [&](int le, floatx4& o0, floatx4& o1) {
        int m = scnt[dn * 2 + le];
        m = m > MAXE ? MAXE : m;
        m = (m + 3) & ~3;              // padded entries point at zero row 2048
        const unsigned short* row = &sidx[dn * 192 + le * 96];
        floatx4 a0 = (floatx4){0.f, 0.f, 0.f, 0.f};
        floatx4 a1 = (floatx4){0.f, 0.f, 0.f, 0.f};
        floatx4 b0 = (floatx4){0.f, 0.f, 0.f, 0.f};
        floatx4 b1 = (floatx4){0.f, 0.f, 0.f, 0.f};
        for (int i = 0; i < m; i += 4) {
            uintx2 w = *(const uintx2*)(row + i);    // 4 indices
            const float* r0 = hp + (size_t)(w[0] & 0xffffu) * DD;
            const float* r1 = hp + (size_t)(w[0] >> 16) * DD;
            const float* r2 = hp + (size_t)(w[1] & 0xffffu) * DD;
            const float* r3 = hp + (size_t)(w[1] >> 16) * DD;
            floatx4 v0 = *(const floatx4*)r0;
            floatx4 v1 = *(const floatx4*)(r0 + 4);
            floatx4 v2 = *(const floatx4*)r1;
            floatx4 v3 = *(const floatx4*)(r1 + 4);
            floatx4 v4 = *(const floatx4*)r2;
            floatx4 v5 = *(const floatx4*)(r2 + 4);
            floatx4 v6 = *(const floatx4*)r3;
            floatx4 v7 = *(const floatx4*)(r3 + 4);
            a0 += v0; a1 += v1; b0 += v2; b1 += v3;
            a0 += v4; a1 += v5; b0 += v6; b1 += v7;
        }
        o0 = a0 + b0;
        o1 = a1 + b1;
    };
    gather_edge(0, e0c0, e0c1);
    gather_edge(1, e1c0, e1c1);

    __syncthreads();   // co-time all 4 waves' stores so L2 merges full lines

    #pragma unroll
    for (int le = 0; le < 2; le++) {
        floatx4 c0 = le ? e1c0 : e0c0;
        floatx4 c1 = le ? e1c1 : e0c1;
        int ge = 2 * ep + le;
        unsigned short hs[8], ls[8];
        #pragma unroll
        for (int j = 0; j < 4; j++) {
            split2(c0[j], hs[j], ls[j]);
            split2(c1[j], hs[4 + j], ls[4 + j]);
        }
        short8 hv, lv;
        #pragma unroll
        for (int j = 0; j < 8; j++) { hv[j] = (short)hs[j]; lv[j] = (short)ls[j]; }
        // FO addr: row n0+dn, k = ge*512 + 8*th2 + j
        size_t a = ((size_t)(n0 >> 4) * 512 + ge * 64 + th2) * 128
                 + (size_t)((n0 & 15) + dn) * 8;
        *(short8*)(Gbhi + a) = hv;
        *(short8*)(Gblo + a) = lv;
    }
}

// Split-bf16 MFMA GEMM on FO operands (m97 structure: single 24 KB LDS buffer,
// global_load_lds(16B) staging, 2 barriers/iter). Block 64(M)x32(N), 4 waves
// (2m x 2n), wave 32x16. C = (Ahi+Alo)@(Bhi+Blo)^T (3 products), fp32 acc.
// 1D grids of 1024 blocks (4/CU):
// MODE 0 (prop): K split 2 (kh): block K=2048 of Gbig@WpT; P[kh][o] = acc.
// MODE 1 (zr):   K=1024 (A seg: Ga|HB), N=1024. col<512: zbuf=sigmoid(v+b0);
//                else RH = split(sigmoid(v+b1)*h).
// MODE 2 (fin):  seg split (kh): kh=0: Ga@Wh (K=512), kh=1: RH@Uh; P[kh][o]=acc.
template<int MODE>
__global__ __launch_bounds__(256, 4) void k_gemm8(
    const short* __restrict__ A0hi, const short* __restrict__ A0lo,
    const short* __restrict__ A1hi, const short* __restrict__ A1lo,
    const short* __restrict__ Bhi,  const short* __restrict__ Blo,
    const float* __restrict__ bias0, const float* __restrict__ bias1,
    float* __restrict__ zbuf,
    float* __restrict__ h,
    short* __restrict__ Ohi, short* __restrict__ Olo,
    float* __restrict__ P0, float* __restrict__ P1) {

    __shared__ short S[24][512];   // 24 slots x 1KB = 24 KB (single buffer)

    const int tid = threadIdx.x;
    const int lane = tid & 63;
    const int wave = tid >> 6;
    const int wm = wave >> 1;          // m-half (32 rows)
    const int wn = wave & 1;           // n-tile (16 cols)
    const int quad = lane >> 4;
    const int l16 = lane & 15;

    // 1D grid decode (XCD-banded: dispatch round-robin pbid%8 assumed)
    const int pbid = blockIdx.x;
    const int x = pbid & 7;
    const int j = pbid >> 3;           // 0..127
    const int mband = x * 4 + (j & 3); // 0..31
    int kh, bx;
    if (MODE == 1) { kh = 0; bx = j >> 2; }            // bx 0..31
    else           { kh = (j >> 2) & 1; bx = j >> 3; } // bx 0..15
    const int blockM = mband * 64;
    const int blockN = bx * 32;
    const int mt0 = blockM >> 4, nt0 = blockN >> 4;
    const int KCB = (MODE == 0) ? 512 : 128;           // B row stride (kchunks)
    const int bko = (MODE == 0) ? kh * 256 : (MODE == 2 ? kh * 64 : 0);
    const int Kloc = (MODE == 0) ? 2048 : (MODE == 1 ? 1024 : 512);

    const short* Ahi_s = (MODE == 2 && kh) ? A1hi : A0hi;
    const short* Alo_s = (MODE == 2 && kh) ? A1lo : A0lo;

    floatx4 acc[2];
    acc[0] = (floatx4){0.f, 0.f, 0.f, 0.f};
    acc[1] = (floatx4){0.f, 0.f, 0.f, 0.f};

    // slots: 0..7 A-hi (mt=u>>1, ks=u&1); 8..15 A-lo; 16..23 B (pl=u>>2, ks=(u>>1)&1, nt=u&1)
    auto gaddr = [&](int k0, int s) -> const short* {
        if (s < 16) {
            int pl = s >> 3, u = s & 7;
            int mt = u >> 1, ks = u & 1;
            const short* base;
            int kc, stride;
            if (MODE == 0) {
                base = pl ? A0lo : A0hi;
                kc = kh * 256 + (k0 >> 3) + ks * 4;
                stride = 512;
            } else if (MODE == 1) {
                int seg = k0 >> 9;
                base = seg ? (pl ? A1lo : A1hi) : (pl ? A0lo : A0hi);
                kc = ((k0 & 511) >> 3) + ks * 4;
                stride = 64;
            } else {
                base = pl ? Alo_s : Ahi_s;
                kc = (k0 >> 3) + ks * 4;
                stride = 64;
            }
            return base + ((size_t)(mt0 + mt) * stride + kc) * 128;
        } else {
            int u = s - 16, pl = u >> 2, ks = (u >> 1) & 1, nt = u & 1;
            const short* base = pl ? Blo : Bhi;
            return base + ((size_t)(nt0 + nt) * KCB + bko + (k0 >> 3) + ks * 4) * 128;
        }
    };

    for (int k0 = 0; k0 < Kloc; k0 += 64) {
        // stage: each wave DMAs 6 slots (wave-uniform LDS base + lane*16)
        #pragma unroll
        for (int jj = 0; jj < 6; jj++) {
            int s = jj * 4 + wave;
            gload16(gaddr(k0, s) + lane * 8, &S[s][lane * 8]);
        }
        __syncthreads();   // drains DMA (vmcnt) + ensures all waves staged

        #pragma unroll
        for (int ks = 0; ks < 2; ks++) {
            short8 ah[2], al[2], bh, bl;
            #pragma unroll
            for (int mi = 0; mi < 2; mi++) {
                ah[mi] = *(const short8*)&S[(wm * 2 + mi) * 2 + ks][lane * 8];
                al[mi] = *(const short8*)&S[8 + (wm * 2 + mi) * 2 + ks][lane * 8];
            }
            bh = *(const short8*)&S[16 + ks * 2 + wn][lane * 8];
            bl = *(const short8*)&S[20 + ks * 2 + wn][lane * 8];
            #pragma unroll
            for (int mi = 0; mi < 2; mi++) {
                acc[mi] = __builtin_amdgcn_mfma_f32_16x16x32_bf16(ah[mi], bh, acc[mi], 0, 0, 0);
                acc[mi] = __builtin_amdgcn_mfma_f32_16x16x32_bf16(ah[mi], bl, acc[mi], 0, 0, 0);
                acc[mi] = __builtin_amdgcn_mfma_f32_16x16x32_bf16(al[mi], bh, acc[mi], 0, 0, 0);
            }
        }
        __syncthreads();   // all reads done before next stage overwrites
    }

    // C/D layout (m89-verified): elem r -> row = quad*4+r, col = l16
    float* P = kh ? P1 : P0;
    #pragma unroll
    for (int mi = 0; mi < 2; mi++) {
        int gcol = blockN + wn * 16 + l16;
        #pragma unroll
        for (int r = 0; r < 4; r++) {
            int grow = blockM + wm * 32 + mi * 16 + quad * 4 + r;
            float v = acc[mi][r];
            if (MODE == 0 || MODE == 2) {
                P[(size_t)grow * DD + gcol] = v;
            } else {
                if (gcol < DD) {
                    size_t o = (size_t)grow * DD + gcol;
                    zbuf[o] = 1.f / (1.f + __expf(-(v + bias0[gcol])));
                } else {
                    int c = gcol - DD;
                    size_t o = (size_t)grow * DD + c;
                    float rr = 1.f / (1.f + __expf(-(v + bias1[c])));
                    fo_write(Ohi, Olo, grow, c, rr * h[o]);
                }
            }
        }
    }
}

// Ga = split(P0 + P1 + deg-bias), deg-bias = sum_e cnt[n,e]*b_prop[e] computed inline
__global__ __launch_bounds__(256) void k_combP(const float* __restrict__ P0,
                                               const float* __restrict__ P1,
                                               const int* __restrict__ cnt2,
                                               const float* __restrict__ bp,
                                               short* __restrict__ Gahi,
                                               short* __restrict__ Galo) {
    int n = blockIdx.x, t = threadIdx.x;
    int c = 2 * t;
    float s0 = 0.f, s1 = 0.f;
    #pragma unroll
    for (int e = 0; e < NEDGE; e++) {
        float ce = (float)cnt2[n * NEDGE + e];
        s0 += ce * bp[e * DD + c];
        s1 += ce * bp[e * DD + c + 1];
    }
    size_t o = (size_t)n * DD + c;
    float v0 = P0[o] + P1[o] + s0;
    float v1 = P0[o + 1] + P1[o + 1] + s1;
    fo_write2(Gahi, Galo, n, c, v0, v1);
}

// GRU combine: hn = (1-z)h + z*tanh(P0+P1+bh) -> h, HB (FO), outF
__global__ __launch_bounds__(256) void k_combF(const float* __restrict__ P0,
                                               const float* __restrict__ P1,
                                               const float* __restrict__ bh,
                                               const float* __restrict__ zbuf,
                                               float* __restrict__ h,
                                               short* __restrict__ HBhi,
                                               short* __restrict__ HBlo,
                                               float* __restrict__ outF) {
    int n = blockIdx.x, t = threadIdx.x;
    int c = 2 * t;
    size_t o = (size_t)n * DD + c;
    float hn0, hn1;
    {
        float v = P0[o] + P1[o] + bh[c];
        hn0 = (1.f - zbuf[o]) * h[o] + zbuf[o] * tanhf(v);
    }
    {
        float v = P0[o + 1] + P1[o + 1] + bh[c + 1];
        hn1 = (1.f - zbuf[o + 1]) * h[o + 1] + zbuf[o + 1] * tanhf(v);
    }
    h[o] = hn0;
    h[o + 1] = hn1;
    fo_write2(HBhi, HBlo, n, c, hn0, hn1);
    outF[o] = hn0;
    outF[o + 1] = hn1;
}

extern "C" void kernel_launch(void* const* d_in, const int* in_sizes, int n_in,
                              void* d_out, int out_size, void* d_ws, size_t ws_size,
                              hipStream_t stream) {
    const float* adj = (const float*)d_in[0];
    const float* ann = (const float*)d_in[1];
    const float* Wp  = (const float*)d_in[2];
    const float* bp  = (const float*)d_in[3];
    const float* Wz  = (const float*)d_in[4];
    const float* Uz  = (const float*)d_in[5];
    const float* bz  = (const float*)d_in[6];
    const float* Wr  = (const float*)d_in[7];
    const float* Ur  = (const float*)d_in[8];
    const float* br  = (const float*)d_in[9];
    const float* Wh  = (const float*)d_in[10];
    const float* Uh  = (const float*)d_in[11];
    const float* bh  = (const float*)d_in[12];

    // workspace carve (~77 MB; ws ~512 MB per round-4 fill counters)
    char* p = (char*)d_ws;
    float* h     = (float*)p; p += (size_t)(NNODE + 1) * DD * 4;    // 4 MB (+zero row)
    float* abuf  = (float*)p; p += (size_t)NNODE * DD * 4;          // 4 MB z-buffer
    float* P0    = (float*)p; p += (size_t)NNODE * DD * 4;          // 4 MB split-K partial
    float* P1    = (float*)p; p += (size_t)NNODE * DD * 4;          // 4 MB
    short* Gbhi  = (short*)p; p += (size_t)NNODE * KP * 2;          // 16 MB (FO K=4096)
    short* Gblo  = (short*)p; p += (size_t)NNODE * KP * 2;          // 16 MB
    short* Gahi  = (short*)p; p += (size_t)NNODE * DD * 2;          // 2 MB (FO K=512)
    short* Galo  = (short*)p; p += (size_t)NNODE * DD * 2;
    short* HBhi  = (short*)p; p += (size_t)NNODE * DD * 2;
    short* HBlo  = (short*)p; p += (size_t)NNODE * DD * 2;
    short* RHhi  = (short*)p; p += (size_t)NNODE * DD * 2;
    short* RHlo  = (short*)p; p += (size_t)NNODE * DD * 2;
    short* WpThi = (short*)p; p += (size_t)DD * KP * 2;             // 4 MB (FO N=512,K=4096)
    short* WpTlo = (short*)p; p += (size_t)DD * KP * 2;
    short* ZRhi  = (short*)p; p += (size_t)(2 * DD) * (2 * DD) * 2; // 2 MB (FO N=1024,K=1024)
    short* ZRlo  = (short*)p; p += (size_t)(2 * DD) * (2 * DD) * 2;
    short* HThi  = (short*)p; p += (size_t)DD * (2 * DD) * 2;       // 1 MB (FO N=512,K=1024)
    short* HTlo  = (short*)p; p += (size_t)DD * (2 * DD) * 2;
    unsigned short* idx = (unsigned short*)p;
    p += (size_t)NNODE * NEDGE * MAXE * 2;                          // 3 MB
    int* cnt2 = (int*)p; p += (size_t)NNODE * NEDGE * 4;

    float* outF = (float*)d_out;

    k_init<<<NNODE, 256, 0, stream>>>(ann, h, HBhi, HBlo, cnt2, idx);
    k_build<<<NNODE, 256, 0, stream>>>(adj, cnt2, idx);
    k_transP<<<dim3(KP / 32, DD / 32), 256, 0, stream>>>(Wp, WpThi, WpTlo, KP);
    k_transG<<<dim3(32, 32), 256, 0, stream>>>(Wz, Uz, Wr, Ur, ZRhi, ZRlo);
    k_transG<<<dim3(32, 16), 256, 0, stream>>>(Wh, Uh, Wh, Uh, HThi, HTlo);

    for (int s = 0; s < NSTEPS; s++) {
        k_gather_all<<<2048, 256, 0, stream>>>(h, cnt2, idx, Gbhi, Gblo);
        // prop split-K: P0/P1 = Gbig @ WpT halves
        k_gemm8<0><<<1024, 256, 0, stream>>>(Gbhi, Gblo, nullptr, nullptr,
                                             WpThi, WpTlo, nullptr, nullptr,
                                             nullptr, nullptr, nullptr, nullptr, P0, P1);
        // Ga = split(P0 + P1 + deg-bias)
        k_combP<<<NNODE, 256, 0, stream>>>(P0, P1, cnt2, bp, Gahi, Galo);
        // [z|r]: z -> abuf (fp32), RH = split(sigmoid(.)*h)
        k_gemm8<1><<<1024, 256, 0, stream>>>(Gahi, Galo, HBhi, HBlo,
                                             ZRhi, ZRlo, bz, br,
                                             abuf, h, RHhi, RHlo, nullptr, nullptr);
        // fin split: P0 = Ga@Wh, P1 = RH@Uh
        k_gemm8<2><<<1024, 256, 0, stream>>>(Gahi, Galo, RHhi, RHlo,
                                             HThi, HTlo, nullptr, nullptr,
                                             nullptr, nullptr, nullptr, nullptr, P0, P1);
        // h' = (1-z)h + z*tanh(P0+P1+bh) -> h, HB, d_out
        k_combF<<<NNODE, 256, 0, stream>>>(P0, P1, bh, abuf, h, HBhi, HBlo, outF);
    }
}